// Round 6
// baseline (26329.596 us; speedup 1.0000x reference)
//
#include <hip/hip_runtime.h>
#include <hip/hip_bf16.h>

#define MK_N 8
#define MK_T 8
#define MK_H 256
#define MK_W 256
#define MK_CO 64
#define MK_EPS 1e-5f

// read element idx from p, which is fp32 (isf32=1) or bf16 (isf32=0)
__device__ __forceinline__ float rdv(const void* p, long idx, int isf32) {
  return isf32 ? ((const float*)p)[idx]
               : __bfloat162float(((const __hip_bfloat16*)p)[idx]);
}

__device__ __forceinline__ float ldv(const float* p, long i) { return p[i]; }
__device__ __forceinline__ float ldv(const __hip_bfloat16* p, long i) {
  return __bfloat162float(p[i]);
}
__device__ __forceinline__ void stv(float* p, long i, float v) { p[i] = v; }
__device__ __forceinline__ void stv(__hip_bfloat16* p, long i, float v) {
  p[i] = __float2bfloat16(v);
}

// Inline dtype probe: inspect first 256 uint16 halves of pristine x.
// bf16 N(0,1) data -> ~0 "insane" halves; fp32 data -> ~45% insane.
__device__ __forceinline__ int block_detect_isf(const void* xprobe, int* sflag) {
  if (threadIdx.x < 64) {
    const unsigned short* u16 = (const unsigned short*)xprobe;
    int insane = 0;
#pragma unroll
    for (int j = 0; j < 4; ++j) {
      unsigned short u = u16[threadIdx.x * 4 + j];
      int e = (u >> 7) & 0xFF;
      bool zero = (u & 0x7FFF) == 0;
      if (!(zero || (e >= 0x60 && e <= 0x85))) insane++;
    }
#pragma unroll
    for (int off = 32; off > 0; off >>= 1) insane += __shfl_down(insane, off);
    if (threadIdx.x == 0) *sflag = (insane > 32) ? 1 : 0;
  }
  __syncthreads();
  return *sflag;
}

// ---------------- zero 128 floats ----------------
__global__ void zero128_kernel(float* __restrict__ p) { p[threadIdx.x] = 0.f; }

// ---------------- fused conv: inline gate + expert mix + 5x5 SAME conv ----------------
// One block = one output row (n,o,row); one thread = one output pixel.
// XBF: x is bf16 (layer 2); else dtype resolved by runtime probe.
// TOUT: float (final out) or __hip_bfloat16 (intermediate h).
template <int CI, bool XBF, typename TOUT>
__global__ __launch_bounds__(256) void conv_mode(
    const void* __restrict__ x,       // [N,CI,H,W]
    const void* __restrict__ xprobe,  // pristine original x (for dtype probe)
    const void* __restrict__ t,  const void* __restrict__ gw, const void* __restrict__ gb,
    const void* __restrict__ w5, const void* __restrict__ w3, const void* __restrict__ w1,
    const void* __restrict__ a3, const void* __restrict__ a5,
    TOUT* __restrict__ y,             // [N,CO,H,W] raw conv out
    float* __restrict__ stats)        // [2*CO] or nullptr
{
  __shared__ float wl[CI * 25];
  __shared__ float sg[5], slg[5];
  __shared__ float rs[4], rq[4];
  __shared__ int sflag;

  const int b = blockIdx.x;              // ((n*CO)+o)*H + row
  const int row = b & (MK_H - 1);
  const int o = (b >> 8) & (MK_CO - 1);
  const int n = b >> 14;

  const int isf = block_detect_isf(xprobe, &sflag);

  // gate logits for this (n, o): 5 experts
  if (threadIdx.x < 5) {
    int e = threadIdx.x;
    int grow = e * MK_CO + o;
    float s = rdv(gb, grow, isf);
#pragma unroll
    for (int k = 0; k < MK_T; ++k)
      s += rdv(t, n * MK_T + k, isf) * rdv(gw, grow * MK_T + k, isf);
    slg[e] = s;
  }
  __syncthreads();
  if (threadIdx.x == 0) {
    float m = slg[0];
#pragma unroll
    for (int e = 1; e < 5; ++e) m = fmaxf(m, slg[e]);
    float ex[5], sum = 0.f;
#pragma unroll
    for (int e = 0; e < 5; ++e) { ex[e] = expf(slg[e] - m); sum += ex[e]; }
#pragma unroll
    for (int e = 0; e < 5; ++e) sg[e] = ex[e] / sum;
  }
  __syncthreads();

  // build mixed 5x5xCI kernel for (n,o) into LDS
  for (int idx = threadIdx.x; idx < CI * 25; idx += 256) {
    int i = idx / 25, k = idx % 25, ky = k / 5, kx = k % 5;
    float v = sg[0] * rdv(w5, (o * CI + i) * 25 + k, isf);
    if (ky >= 1 && ky <= 3 && kx >= 1 && kx <= 3) {
      v += sg[1] * rdv(w3, (o * CI + i) * 9 + (ky - 1) * 3 + (kx - 1), isf);
      v += sg[3] * rdv(a3, o * CI + i, isf) * (1.f / 27.f);
    }
    if (ky == 2 && kx == 2) v += sg[2] * rdv(w1, o * CI + i, isf);
    v += sg[4] * rdv(a5, o * CI + i, isf) * (1.f / 125.f);
    wl[idx] = v;
  }
  __syncthreads();

  const int col = threadIdx.x;
  const long xbase = (long)n * CI * (MK_H * MK_W);
  float acc = 0.f;
  for (int c = 0; c < CI; ++c) {
    const float* wc = &wl[c * 25];
    const long pbase = xbase + (long)c * (MK_H * MK_W);
#pragma unroll
    for (int ky = 0; ky < 5; ++ky) {
      int yy = row + ky - 2;
      if ((unsigned)yy >= MK_H) continue;
      const long rbase = pbase + (long)yy * MK_W;
#pragma unroll
      for (int kx = 0; kx < 5; ++kx) {
        int xx = col + kx - 2;
        float v = 0.f;
        if ((unsigned)xx < MK_W)
          v = XBF ? __bfloat162float(((const __hip_bfloat16*)x)[rbase + xx])
                  : rdv(x, rbase + xx, isf);
        acc = fmaf(wc[ky * 5 + kx], v, acc);
      }
    }
  }

  stv(y, ((long)(n * MK_CO + o) * MK_H + row) * MK_W + col, acc);

  if (stats) {
    float s = acc, q = acc * acc;
#pragma unroll
    for (int off = 32; off > 0; off >>= 1) {
      s += __shfl_down(s, off);
      q += __shfl_down(q, off);
    }
    int lane = threadIdx.x & 63, wv = threadIdx.x >> 6;
    if (lane == 0) { rs[wv] = s; rq[wv] = q; }
    __syncthreads();
    if (threadIdx.x == 0) {
      atomicAdd(&stats[o], rs[0] + rs[1] + rs[2] + rs[3]);
      atomicAdd(&stats[MK_CO + o], rq[0] + rq[1] + rq[2] + rq[3]);
    }
  }
}

// ---------------- standalone stats pass over fp32 tensor (layer 2) ----------------
__global__ __launch_bounds__(256) void stats_pass_kernel(const float* __restrict__ y,
                                                         float* __restrict__ stats) {
  __shared__ float rs[4], rq[4];
  const int b = blockIdx.x;
  const int row = b & (MK_H - 1);
  const int o = (b >> 8) & (MK_CO - 1);
  const int n = b >> 14;
  float v = y[((long)(n * MK_CO + o) * MK_H + row) * MK_W + threadIdx.x];
  float s = v, q = v * v;
#pragma unroll
  for (int off = 32; off > 0; off >>= 1) {
    s += __shfl_down(s, off);
    q += __shfl_down(q, off);
  }
  int lane = threadIdx.x & 63, wv = threadIdx.x >> 6;
  if (lane == 0) { rs[wv] = s; rq[wv] = q; }
  __syncthreads();
  if (threadIdx.x == 0) {
    atomicAdd(&stats[o], rs[0] + rs[1] + rs[2] + rs[3]);
    atomicAdd(&stats[MK_CO + o], rq[0] + rq[1] + rq[2] + rq[3]);
  }
}

// ---------------- finalize BN: stats -> per-channel scale/shift ----------------
__global__ void finalize_mode_kernel(const float* __restrict__ stats,
                                     float* __restrict__ params,
                                     const void* __restrict__ gamma,
                                     const void* __restrict__ beta,
                                     const void* __restrict__ xprobe) {
  __shared__ int sflag;
  int isf = block_detect_isf(xprobe, &sflag);
  int o = threadIdx.x;
  if (o < MK_CO) {
    const float M = (float)(MK_N * MK_H * MK_W);
    float mean = stats[o] / M;
    float var = stats[MK_CO + o] / M - mean * mean;
    float inv = rsqrtf(var + MK_EPS);
    float sc = rdv(gamma, o, isf) * inv;
    params[o] = sc;
    params[MK_CO + o] = rdv(beta, o, isf) - mean * sc;
  }
}

// ---------------- in-place BN + ReLU ----------------
template <typename T>
__global__ __launch_bounds__(256) void bn_relu_mode(T* __restrict__ y,
                                                    const float* __restrict__ params) {
  long i = (long)blockIdx.x * 256 + threadIdx.x;
  int ch = (int)((i >> 16) & (MK_CO - 1));  // 65536 elements per plane
  float v = ldv(y, i);
  v = fmaxf(fmaf(v, params[ch], params[MK_CO + ch]), 0.f);
  stv(y, i, v);
}

extern "C" void kernel_launch(void* const* d_in, const int* in_sizes, int n_in,
                              void* d_out, int out_size, void* d_ws, size_t ws_size,
                              hipStream_t stream) {
  const void* x     = d_in[0];
  const void* t     = d_in[1];
  const void* w5_1  = d_in[2];
  const void* w3_1  = d_in[3];
  const void* w1_1  = d_in[4];
  const void* a3_1  = d_in[5];
  const void* a5_1  = d_in[6];
  const void* gw_1  = d_in[7];
  const void* gb_1  = d_in[8];
  const void* gamma_1 = d_in[9];
  const void* beta_1  = d_in[10];
  const void* w5_2  = d_in[11];
  const void* w3_2  = d_in[12];
  const void* w1_2  = d_in[13];
  const void* a3_2  = d_in[14];
  const void* a5_2  = d_in[15];
  const void* gw_2  = d_in[16];
  const void* gb_2  = d_in[17];
  const void* gamma_2 = d_in[18];
  const void* beta_2  = d_in[19];

  // d_ws usage: EXACTLY 64 MiB (the bf16 intermediate h). Nothing else.
  __hip_bfloat16* h = (__hip_bfloat16*)d_ws;   // [N,CO,H,W] bf16 = 67,108,864 B

  // layer-1 scratch lives in d_out head (fp32 buffer; free until conv2 overwrites)
  float* st1 = (float*)d_out;          // floats [0,128): sum, sumsq
  float* pr1 = (float*)d_out + 128;    // floats [128,256): scale, shift

  // layer-2 scratch reuses h's head (h is dead after conv2)
  float* st2 = (float*)d_ws;           // floats [0,128)
  float* pr2 = (float*)d_ws + 128;     // floats [128,256)

  float* out = (float*)d_out;          // FP32 output, [N,CO,H,W]
  const int NBLK = MK_N * MK_CO * MK_H;  // 131072

  // ---- layer 1 ----
  zero128_kernel<<<1, 128, 0, stream>>>(st1);
  conv_mode<32, false, __hip_bfloat16><<<NBLK, 256, 0, stream>>>(
      x, x, t, gw_1, gb_1, w5_1, w3_1, w1_1, a3_1, a5_1, h, st1);
  finalize_mode_kernel<<<1, 64, 0, stream>>>(st1, pr1, gamma_1, beta_1, x);
  bn_relu_mode<__hip_bfloat16><<<NBLK, 256, 0, stream>>>(h, pr1);

  // ---- layer 2 ----
  conv_mode<64, true, float><<<NBLK, 256, 0, stream>>>(
      h, x, t, gw_2, gb_2, w5_2, w3_2, w1_2, a3_2, a5_2, out, (float*)nullptr);
  zero128_kernel<<<1, 128, 0, stream>>>(st2);
  stats_pass_kernel<<<NBLK, 256, 0, stream>>>(out, st2);
  finalize_mode_kernel<<<1, 64, 0, stream>>>(st2, pr2, gamma_2, beta_2, x);
  bn_relu_mode<float><<<NBLK, 256, 0, stream>>>(out, pr2);
}

// Round 7
// 2976.736 us; speedup vs baseline: 8.8451x; 8.8451x over previous
//
#include <hip/hip_runtime.h>
#include <hip/hip_bf16.h>

#define MK_N 8
#define MK_T 8
#define MK_H 256
#define MK_W 256
#define MK_CO 64
#define MK_EPS 1e-5f

typedef __attribute__((ext_vector_type(8))) short short8;
typedef __attribute__((ext_vector_type(4))) short short4v;
typedef __attribute__((ext_vector_type(4))) float f32x4;

// read element idx from p, which is fp32 (isf32=1) or bf16 (isf32=0)
__device__ __forceinline__ float rdv(const void* p, long idx, int isf32) {
  return isf32 ? ((const float*)p)[idx]
               : __bfloat162float(((const __hip_bfloat16*)p)[idx]);
}

__device__ __forceinline__ short f2bf_s(float f) {
  __hip_bfloat16 b = __float2bfloat16(f);
  union { __hip_bfloat16 b; short s; } u; u.b = b; return u.s;
}
__device__ __forceinline__ float bfu2f(unsigned short s) {
  return __uint_as_float((unsigned)s << 16);
}

// Inline dtype probe on pristine x: bf16 -> sane exponents; fp32 -> ~45% insane.
__device__ __forceinline__ int block_detect_isf(const void* xprobe, int* sflag) {
  if (threadIdx.x < 64) {
    const unsigned short* u16 = (const unsigned short*)xprobe;
    int insane = 0;
#pragma unroll
    for (int j = 0; j < 4; ++j) {
      unsigned short u = u16[threadIdx.x * 4 + j];
      int e = (u >> 7) & 0xFF;
      bool zero = (u & 0x7FFF) == 0;
      if (!(zero || (e >= 0x60 && e <= 0x85))) insane++;
    }
#pragma unroll
    for (int off = 32; off > 0; off >>= 1) insane += __shfl_down(insane, off);
    if (threadIdx.x == 0) *sflag = (insane > 32) ? 1 : 0;
  }
  __syncthreads();
  return *sflag;
}

__global__ void zero128_kernel(float* __restrict__ p) { p[threadIdx.x] = 0.f; }

// ---------------- x (NCHW, fp32|bf16) -> NHWC bf16 ----------------
__global__ __launch_bounds__(256) void x_to_nhwc(const void* __restrict__ x,
                                                 short* __restrict__ xo,
                                                 const void* __restrict__ xprobe) {
  __shared__ float xl[32 * 65];
  __shared__ int sflag;
  int isf = block_detect_isf(xprobe, &sflag);
  int n = blockIdx.z, y = blockIdx.y, x0 = blockIdx.x * 64;
  int tid = threadIdx.x;
  {
    int c = tid >> 3, ch = tid & 7;
    long base = ((long)(n * 32 + c) * 256 + y) * 256 + x0 + ch * 8;
#pragma unroll
    for (int j = 0; j < 8; ++j) xl[c * 65 + ch * 8 + j] = rdv(x, base + j, isf);
  }
  __syncthreads();
  {
    int xi = tid >> 2, cc = tid & 3;
    short8 v;
#pragma unroll
    for (int j = 0; j < 8; ++j) v[j] = f2bf_s(xl[(cc * 8 + j) * 65 + xi]);
    *(short8*)&xo[(((long)(n * 256 + y) * 256) + x0 + xi) * 32 + cc * 8] = v;
  }
}

// ---------------- MFMA implicit-GEMM conv ----------------
// Block: 256 thr (4 waves). Tile: [CO=64] x [4 rows] x [64 cols], sample n.
// 25 shifted GEMMs, K = channels (CI=32: 1 K-chunk; CI=64: 2 c-halves).
// Weights: gate+mix computed in-kernel per shift into double-buffered LDS.
template <int CI, bool FINAL>
__global__ __launch_bounds__(256, 2) void conv_mfma(
    const short* __restrict__ xsrc,   // NHWC bf16 [8][256][256][CI]
    const void* __restrict__ xprobe,
    const void* __restrict__ t, const void* __restrict__ gw, const void* __restrict__ gb,
    const void* __restrict__ w5, const void* __restrict__ w3, const void* __restrict__ w1,
    const void* __restrict__ a3, const void* __restrict__ a5,
    void* __restrict__ outp)          // FINAL ? float* NCHW : short* NHWC bf16
{
  __shared__ short xt[8 * 68 * 40];    // 43520 B, c-half staged, pad 40
  __shared__ short wbuf[2 * 64 * 40];  // 10240 B, double-buffered W panel
  __shared__ float slog[320], sgate[320];
  __shared__ int sflag;

  const int tid = threadIdx.x;
  const int x0 = blockIdx.x * 64;
  const int r0 = blockIdx.y * 4;
  const int n = blockIdx.z;

  const int isf = block_detect_isf(xprobe, &sflag);

  // ---- gates for (n, all o) ----
  for (int eo = tid; eo < 320; eo += 256) {
    int e = eo >> 6, o = eo & 63;
    long row = e * 64 + o;
    float s = rdv(gb, row, isf);
#pragma unroll
    for (int k = 0; k < MK_T; ++k)
      s += rdv(t, n * MK_T + k, isf) * rdv(gw, row * MK_T + k, isf);
    slog[e * 64 + o] = s;
  }
  __syncthreads();
  if (tid < 64) {
    float m = slog[tid];
#pragma unroll
    for (int e = 1; e < 5; ++e) m = fmaxf(m, slog[e * 64 + tid]);
    float tmp[5], sum = 0.f;
#pragma unroll
    for (int e = 0; e < 5; ++e) { tmp[e] = expf(slog[e * 64 + tid] - m); sum += tmp[e]; }
    float inv = 1.f / sum;
#pragma unroll
    for (int e = 0; e < 5; ++e) sgate[tid * 5 + e] = tmp[e] * inv;
  }
  __syncthreads();

  // per-thread mixing role: o = tid>>2, 8 channels at gq*8
  const int mo = tid >> 2, gq = tid & 3;
  float ge[5];
#pragma unroll
  for (int e = 0; e < 5; ++e) ge[e] = sgate[mo * 5 + e];

  const int lane = tid & 63, w = tid >> 6;
  const int quad = lane >> 4, l15 = lane & 15;

  int baseB[4];
#pragma unroll
  for (int p = 0; p < 4; ++p)
    baseB[p] = (w * 68 + p * 16 + l15) * 40 + quad * 8;
  int baseA[4];
#pragma unroll
  for (int ot = 0; ot < 4; ++ot)
    baseA[ot] = (ot * 16 + l15) * 40 + quad * 8;

  f32x4 acc[4][4];
#pragma unroll
  for (int ot = 0; ot < 4; ++ot)
#pragma unroll
    for (int p = 0; p < 4; ++p) acc[ot][p] = f32x4{0.f, 0.f, 0.f, 0.f};

  const int HC = CI / 32;
#pragma unroll 1
  for (int hc = 0; hc < HC; ++hc) {
    const int cbase = hc * 32;

    // preload shift-invariant expert values for this thread's 8 (o,c) slots
    float pw1[8], pa3[8], pa5[8];
#pragma unroll
    for (int j = 0; j < 8; ++j) {
      long oc = (long)mo * CI + cbase + gq * 8 + j;
      pw1[j] = rdv(w1, oc, isf);
      pa3[j] = rdv(a3, oc, isf) * (1.f / 27.f);
      pa5[j] = rdv(a5, oc, isf) * (1.f / 125.f);
    }

    // ---- stage x tile (8 rows x 68 cols x 32 ch) ----
    for (int idx = tid; idx < 8 * 68 * 4; idx += 256) {
      int r = idx / (68 * 4);
      int rem = idx - r * (68 * 4);
      int col = rem >> 2, ch = rem & 3;
      int gy = r0 - 2 + r, gx = x0 - 2 + col;
      short8 v = short8{0, 0, 0, 0, 0, 0, 0, 0};
      if ((unsigned)gy < 256u && (unsigned)gx < 256u)
        v = *(const short8*)&xsrc[(((long)(n * 256 + gy) * 256) + gx) * CI + cbase + ch * 8];
      *(short8*)&xt[(r * 68 + col) * 40 + ch * 8] = v;
    }

    // ---- mix W for shift s into wbuf[buf] ----
    auto mix = [&](int s, int buf) {
      int ky = s / 5, kx = s - ky * 5;
      bool in3 = (ky >= 1 && ky <= 3 && kx >= 1 && kx <= 3);
      short8 pk;
#pragma unroll
      for (int j = 0; j < 8; ++j) {
        long oc = (long)mo * CI + cbase + gq * 8 + j;
        float v = ge[0] * rdv(w5, oc * 25 + s, isf);
        if (in3) {
          v += ge[1] * rdv(w3, oc * 9 + (ky - 1) * 3 + (kx - 1), isf);
          v += ge[3] * pa3[j];
        }
        if (s == 12) v += ge[2] * pw1[j];
        v += ge[4] * pa5[j];
        pk[j] = f2bf_s(v);
      }
      *(short8*)&wbuf[buf * 2560 + mo * 40 + gq * 8] = pk;
    };

    mix(0, 0);
    __syncthreads();

#pragma unroll
    for (int s = 0; s < 25; ++s) {
      if (s < 24) mix(s + 1, (s + 1) & 1);
      const int ky = s / 5, kx = s - ky * 5;
      const int koff = (ky * 68 + kx) * 40;
      const short* wb = &wbuf[(s & 1) * 2560];
      short8 af[4], bf[4];
#pragma unroll
      for (int ot = 0; ot < 4; ++ot) af[ot] = *(const short8*)&wb[baseA[ot]];
#pragma unroll
      for (int p = 0; p < 4; ++p) bf[p] = *(const short8*)&xt[baseB[p] + koff];
#pragma unroll
      for (int ot = 0; ot < 4; ++ot)
#pragma unroll
        for (int p = 0; p < 4; ++p)
          acc[ot][p] = __builtin_amdgcn_mfma_f32_16x16x32_bf16(af[ot], bf[p], acc[ot][p], 0, 0, 0);
      __syncthreads();
    }
  }

  if (FINAL) {
    // fp32 NCHW direct stores
    float* out = (float*)outp;
#pragma unroll
    for (int ot = 0; ot < 4; ++ot)
#pragma unroll
      for (int p = 0; p < 4; ++p)
#pragma unroll
        for (int r = 0; r < 4; ++r) {
          int oo = ot * 16 + quad * 4 + r;
          long off = ((long)(n * 64 + oo) << 16) + (r0 + w) * 256 + x0 + p * 16 + l15;
          out[off] = acc[ot][p][r];
        }
  } else {
    // bf16 NHWC via LDS bounce (alias xt; all reads done: loop ended with barrier)
    short* cbuf = xt;  // need 4*64*72 = 18432 <= 21760
#pragma unroll
    for (int ot = 0; ot < 4; ++ot)
#pragma unroll
      for (int p = 0; p < 4; ++p) {
        short4v pk;
#pragma unroll
        for (int r = 0; r < 4; ++r) pk[r] = f2bf_s(acc[ot][p][r]);
        *(short4v*)&cbuf[(w * 64 + p * 16 + l15) * 72 + ot * 16 + quad * 4] = pk;
      }
    __syncthreads();
    short* hout = (short*)outp;
    for (int idx = tid; idx < 2048; idx += 256) {
      int w2 = idx >> 9, rem = idx & 511;
      int px = rem >> 3, ch = rem & 7;
      short8 v = *(const short8*)&cbuf[(w2 * 64 + px) * 72 + ch * 8];
      *(short8*)&hout[(((long)(n * 256 + r0 + w2) * 256) + x0 + px) * 64 + ch * 8] = v;
    }
  }
}

// ---------------- BN stats over NHWC bf16 (c = idx & 63) ----------------
__global__ __launch_bounds__(256) void stats_nhwc(const unsigned short* __restrict__ h,
                                                  float* __restrict__ stats) {
  __shared__ float rs[256], rq[256];
  int tid = threadIdx.x;
  long base = (long)blockIdx.x * 32768 + tid;
  float s = 0.f, q = 0.f;
#pragma unroll 4
  for (int i = 0; i < 128; ++i) {
    float v = bfu2f(h[base + (long)i * 256]);
    s += v; q += v * v;
  }
  rs[tid] = s; rq[tid] = q;
  __syncthreads();
  if (tid < 64) {
    s = rs[tid] + rs[tid + 64] + rs[tid + 128] + rs[tid + 192];
    q = rq[tid] + rq[tid + 64] + rq[tid + 128] + rq[tid + 192];
    atomicAdd(&stats[tid], s);
    atomicAdd(&stats[64 + tid], q);
  }
}

// ---------------- finalize BN: stats -> per-channel scale/shift ----------------
__global__ void finalize_mode_kernel(const float* __restrict__ stats,
                                     float* __restrict__ params,
                                     const void* __restrict__ gamma,
                                     const void* __restrict__ beta,
                                     const void* __restrict__ xprobe) {
  __shared__ int sflag;
  int isf = block_detect_isf(xprobe, &sflag);
  int o = threadIdx.x;
  if (o < MK_CO) {
    const float M = (float)(MK_N * MK_H * MK_W);
    float mean = stats[o] / M;
    float var = stats[MK_CO + o] / M - mean * mean;
    float inv = rsqrtf(var + MK_EPS);
    float sc = rdv(gamma, o, isf) * inv;
    params[o] = sc;
    params[MK_CO + o] = rdv(beta, o, isf) - mean * sc;
  }
}

// ---------------- in-place BN+ReLU on NHWC bf16 (uint4 = 8 consecutive c) ----------------
__global__ __launch_bounds__(256) void bnrelu_nhwc(uint4* __restrict__ h,
                                                   const float* __restrict__ pr) {
  long i4 = (long)blockIdx.x * 256 + threadIdx.x;
  int c0 = ((int)i4 & 7) * 8;
  uint4 v = h[i4];
  unsigned* u = (unsigned*)&v;
#pragma unroll
  for (int k = 0; k < 4; ++k) {
    int c = c0 + 2 * k;
    float f0 = bfu2f((unsigned short)(u[k] & 0xFFFF));
    float f1 = bfu2f((unsigned short)(u[k] >> 16));
    f0 = fmaxf(fmaf(f0, pr[c], pr[64 + c]), 0.f);
    f1 = fmaxf(fmaf(f1, pr[c + 1], pr[64 + c + 1]), 0.f);
    unsigned lo = (unsigned)(unsigned short)f2bf_s(f0);
    unsigned hi = (unsigned)(unsigned short)f2bf_s(f1);
    u[k] = lo | (hi << 16);
  }
  h[i4] = v;
}

// ---------------- stats over fp32 NCHW ----------------
__global__ __launch_bounds__(256) void stats_pass_kernel(const float* __restrict__ y,
                                                         float* __restrict__ stats) {
  __shared__ float rs[4], rq[4];
  const int b = blockIdx.x;
  const int row = b & (MK_H - 1);
  const int o = (b >> 8) & (MK_CO - 1);
  const int n = b >> 14;
  float v = y[((long)(n * MK_CO + o) * MK_H + row) * MK_W + threadIdx.x];
  float s = v, q = v * v;
#pragma unroll
  for (int off = 32; off > 0; off >>= 1) {
    s += __shfl_down(s, off);
    q += __shfl_down(q, off);
  }
  int lane = threadIdx.x & 63, wv = threadIdx.x >> 6;
  if (lane == 0) { rs[wv] = s; rq[wv] = q; }
  __syncthreads();
  if (threadIdx.x == 0) {
    atomicAdd(&stats[o], rs[0] + rs[1] + rs[2] + rs[3]);
    atomicAdd(&stats[MK_CO + o], rq[0] + rq[1] + rq[2] + rq[3]);
  }
}

// ---------------- in-place BN + ReLU, fp32 NCHW ----------------
__global__ __launch_bounds__(256) void bn_relu_f32(float* __restrict__ y,
                                                   const float* __restrict__ params) {
  long i = (long)blockIdx.x * 256 + threadIdx.x;
  int ch = (int)((i >> 16) & (MK_CO - 1));
  float v = y[i];
  v = fmaxf(fmaf(v, params[ch], params[MK_CO + ch]), 0.f);
  y[i] = v;
}

extern "C" void kernel_launch(void* const* d_in, const int* in_sizes, int n_in,
                              void* d_out, int out_size, void* d_ws, size_t ws_size,
                              hipStream_t stream) {
  const void* x     = d_in[0];
  const void* t     = d_in[1];
  const void* w5_1  = d_in[2];
  const void* w3_1  = d_in[3];
  const void* w1_1  = d_in[4];
  const void* a3_1  = d_in[5];
  const void* a5_1  = d_in[6];
  const void* gw_1  = d_in[7];
  const void* gb_1  = d_in[8];
  const void* gamma_1 = d_in[9];
  const void* beta_1  = d_in[10];
  const void* w5_2  = d_in[11];
  const void* w3_2  = d_in[12];
  const void* w1_2  = d_in[13];
  const void* a3_2  = d_in[14];
  const void* a5_2  = d_in[15];
  const void* gw_2  = d_in[16];
  const void* gb_2  = d_in[17];
  const void* gamma_2 = d_in[18];
  const void* beta_2  = d_in[19];

  // ws: EXACTLY 64 MiB — h (NHWC bf16). Head reused for layer-2 stats after conv2.
  short* h = (short*)d_ws;
  float* st2 = (float*)d_ws;
  float* pr2 = (float*)d_ws + 128;

  // d_out doubles as scratch until conv2 overwrites it:
  short* x_nhwc = (short*)d_out;                          // 33,554,432 B
  float* st1 = (float*)((char*)d_out + 33554432);
  float* pr1 = st1 + 128;
  float* out = (float*)d_out;                             // final fp32 NCHW

  // ---- layer 1 ----
  x_to_nhwc<<<dim3(4, 256, 8), 256, 0, stream>>>(x, x_nhwc, x);
  zero128_kernel<<<1, 128, 0, stream>>>(st1);
  conv_mfma<32, false><<<dim3(4, 64, 8), 256, 0, stream>>>(
      x_nhwc, x, t, gw_1, gb_1, w5_1, w3_1, w1_1, a3_1, a5_1, h);
  stats_nhwc<<<1024, 256, 0, stream>>>((const unsigned short*)h, st1);
  finalize_mode_kernel<<<1, 64, 0, stream>>>(st1, pr1, gamma_1, beta_1, x);
  bnrelu_nhwc<<<16384, 256, 0, stream>>>((uint4*)h, pr1);

  // ---- layer 2 ----
  conv_mfma<64, true><<<dim3(4, 64, 8), 256, 0, stream>>>(
      h, x, t, gw_2, gb_2, w5_2, w3_2, w1_2, a3_2, a5_2, out);
  zero128_kernel<<<1, 128, 0, stream>>>(st2);
  stats_pass_kernel<<<MK_N * MK_CO * MK_H, 256, 0, stream>>>(out, st2);
  finalize_mode_kernel<<<1, 64, 0, stream>>>(st2, pr2, gamma_2, beta_2, x);
  bn_relu_f32<<<MK_N * MK_CO * MK_H, 256, 0, stream>>>(out, pr2);
}